// Round 8
// baseline (521.206 us; speedup 1.0000x reference)
//
#include <hip/hip_runtime.h>

constexpr int B = 64, T = 128, M = 8, KLEAF = 5, KR = 6, N = 48, E = 16, H = 32;
constexpr int BNR = B * N;              // 3072 rows
constexpr int NG  = B * T;              // 8192 graphs
constexpr int BNP = 16;                 // BN stat partitions
constexpr long long R_SIZE = (long long)B * T * N * H;  // 12582912

#define DEVI __device__ __forceinline__

DEVI float frcp(float x) { return __builtin_amdgcn_rcpf(x); }
DEVI float sigm(float x) { return frcp(1.f + __expf(-x)); }
DEVI float tanh_(float x) {
  float a = __expf(2.f * fabsf(x));
  float r = 1.f - 2.f * frcp(a + 1.f);
  return x >= 0.f ? r : -r;
}

// ---------------- K1: root aggregation + phi MLP → v_ws (T, B*N, E) ----------
__global__ __launch_bounds__(256) void k_phi(
    const float* __restrict__ feat, const float* __restrict__ w1,
    const float* __restrict__ b1, const float* __restrict__ w2,
    const float* __restrict__ b2, float* __restrict__ v_ws)
{
  int gid = blockIdx.x * 256 + threadIdx.x;
  if (gid >= B * T * N) return;
  int nn = gid % N;        // node within graph = m*KR + k
  int bt = gid / N;        // b*T + t
  int m = nn / KR, k = nn % KR;
  int t = bt % T, b = bt / T;
  const float* fp = feat + ((size_t)bt * M + m) * (KLEAF * 3);
  float x0, x1, x2;
  if (k < KLEAF) {
    x0 = fp[k * 3 + 0]; x1 = fp[k * 3 + 1]; x2 = fp[k * 3 + 2];
  } else {
    float sx = 0.f, sy = 0.f, sw = 0.f, av = 0.f;
#pragma unroll
    for (int kp = 0; kp < KLEAF; kp++) {
      float fx = fp[kp * 3], fy = fp[kp * 3 + 1], fv = fp[kp * 3 + 2];
      float w = fv > 0.5f ? 1.f : 0.f;
      sx += fx * w; sy += fy * w; sw += w; av = fmaxf(av, w);
    }
    float dn = fmaxf(sw, 1.f);
    x0 = sx / dn; x1 = sy / dn; x2 = av;
  }
  float hd[E];
#pragma unroll
  for (int e = 0; e < E; e++) {
    float v = b1[e] + x0 * w1[0 * E + e] + x1 * w1[1 * E + e] + x2 * w1[2 * E + e];
    hd[e] = v > 0.f ? v : 0.f;
  }
  float* vo = v_ws + ((size_t)t * BNR + (size_t)b * N + nn) * E;
#pragma unroll
  for (int e2 = 0; e2 < E; e2++) {
    float acc = b2[e2];
#pragma unroll
    for (int e = 0; e < E; e++) acc += hd[e] * w2[e * E + e2];
    vo[e2] = acc;
  }
}

// ------------- K2/K5: LSTM, 1 gate row per lane, 2 waves per row -------------
// Block = 256 thr = 4 waves = 2 rows. wave = (pr<<1)|wsel: wsel0 owns {i,f},
// wsel1 owns {g,o}; lane (hi,j): gate = wsel*64 + hi*32 + j. Per-lane weights
// = EE+32 floats -> small enough that the allocator keeps them in VGPRs (the
// 2-gates/lane variant needed ~190 live floats and got reloads every step).
// x row staged in LDS (parity dbuf); gates exchanged via LDS (parity dbuf);
// ONE __syncthreads per step. Race-freedom: writes to buffer[par^1] at step t
// happen after barrier(t-1), and all reads of buffer[par^1] at step t+1 occur
// before barrier(t+1); any rewrite is at step t+2, after barrier(t+1) -> the
// single barrier per step fully orders producer/consumer on each parity.
// h stays wave-private: every wave redundantly computes the identical c/h
// (same LDS inputs, deterministic fp) into its own hl[wave] -> no 2nd barrier.
template <int EE, int MODE>
__global__ __launch_bounds__(256) void k_lstm(
    const float* __restrict__ x, const float* __restrict__ wih,
    const float* __restrict__ whh, const float* __restrict__ bih,
    const float* __restrict__ bhh, float* __restrict__ dout)
{
  constexpr int X4 = EE / 4;
  int tid = threadIdx.x;
  int wave = tid >> 6;
  int pr_ = wave >> 1;          // row within block (0,1)
  int wsel = wave & 1;          // 0: {i,f}  1: {g,o}
  int lane = tid & 63;
  int j = lane & 31, hi = lane >> 5;
  int row = blockIdx.x * 2 + pr_;
  int b = row / N, n = row % N;
  int gate = wsel * 64 + hi * 32 + j;

  float Wx[EE], Wh[32];
#pragma unroll
  for (int e = 0; e < EE; e++) Wx[e] = wih[gate * EE + e];
#pragma unroll
  for (int k = 0; k < 32; k++) Wh[k] = whh[gate * 32 + k];
  float bs = bih[gate] + bhh[gate];

  __shared__ __align__(16) float hl[4][32];          // per-wave h copy
  __shared__ __align__(16) float xl[2][2][EE];       // [pr][parity][EE]
  __shared__ float gx[2][2][2][2][32];               // [pr][par][wsel][hi][j]

  if (hi == 0) hl[wave][j] = 0.f;                    // own-wave init, in-order
  const float* xrow = x + (size_t)row * EE;
  constexpr size_t XST = (size_t)BNR * EE;           // per-t stride in floats
  if (wsel == 0 && lane < X4)
    ((float4*)xl[pr_][0])[lane] = ((const float4*)xrow)[lane];
  __syncthreads();

  float c = 0.f;
  float* prp = dout + ((size_t)b * T * N + n) * H + j;
  float* php = dout + R_SIZE + ((size_t)b * T * N + n) * 2 * H + (MODE == 1 ? H : 0) + j;

  for (int t = 0; t < T; t++) {
    int par = t & 1;
    // prefetch x_{t+1} into regs (HBM latency hides under the FMAs)
    float4 xnv = {0, 0, 0, 0};
    int tn = t + 1 < T ? t + 1 : t;
    if (wsel == 0 && lane < X4)
      xnv = ((const float4*)(xrow + (size_t)tn * XST))[lane];
    // gate pre-activation: a = bs + Wx.x_t + Wh.h_{t-1}
    float a0 = bs, a1 = 0.f, a2 = 0.f, a3 = 0.f;
    const float4* xp4 = (const float4*)xl[pr_][par];
#pragma unroll
    for (int q = 0; q < X4; q++) {
      float4 xv = xp4[q];              // LDS broadcast
      a0 += Wx[4 * q + 0] * xv.x; a1 += Wx[4 * q + 1] * xv.y;
      a2 += Wx[4 * q + 2] * xv.z; a3 += Wx[4 * q + 3] * xv.w;
    }
    const float4* hp4 = (const float4*)hl[wave];
#pragma unroll
    for (int q = 0; q < 8; q++) {
      float4 hv = hp4[q];              // LDS broadcast (own wave's copy)
      a0 += Wh[4 * q + 0] * hv.x; a1 += Wh[4 * q + 1] * hv.y;
      a2 += Wh[4 * q + 2] * hv.z; a3 += Wh[4 * q + 3] * hv.w;
    }
    float a = (a0 + a1) + (a2 + a3);
    // activation: wsel0 -> sigm(i/f); wsel1 -> hi ? sigm(o) : tanh(g)
    float act = (wsel == 0) ? sigm(a) : (hi ? sigm(a) : tanh_(a));
    gx[pr_][par][wsel][hi][j] = act;
    // stage x_{t+1} (parity^1)
    if (wsel == 0 && lane < X4)
      ((float4*)xl[pr_][par ^ 1])[lane] = xnv;
    __syncthreads();
    // combine (all waves redundantly; only hi==0 lanes active)
    if (hi == 0) {
      float iv = gx[pr_][par][0][0][j];
      float fv = gx[pr_][par][0][1][j];
      float gv = gx[pr_][par][1][0][j];
      float ov = gx[pr_][par][1][1][j];
      c = fv * c + iv * gv;
      float hnew = ov * tanh_(c);
      hl[wave][j] = hnew;              // own-wave write, in-order vs next read
      if (wsel == 0) {
        if (MODE == 0) { *prp = hnew; *php = hnew; }
        else { *php = hnew; }
      }
    }
    prp += N * H; php += N * 2 * H;
  }
}

// ---------------- K3a: BN partial stats per (t, partition) -------------------
__global__ __launch_bounds__(256) void k_bn1(
    const float* __restrict__ r, float* __restrict__ part)
{
  int t = blockIdx.x, p = blockIdx.y;
  int c = threadIdx.x & 31, rg = threadIdx.x >> 5;
  constexpr int RPP = BNR / BNP;   // 192 rows per partition
  float s = 0.f, s2 = 0.f;
  for (int row = p * RPP + rg; row < (p + 1) * RPP; row += 8) {
    int b = row / N, n = row % N;
    float x = r[((size_t)b * T + t) * N * H + (size_t)n * H + c];
    s += x; s2 += x * x;
  }
  __shared__ float sm[2][8][32];
  sm[0][rg][c] = s; sm[1][rg][c] = s2;
  __syncthreads();
  if (rg == 0) {
    float ss = 0.f, ss2 = 0.f;
#pragma unroll
    for (int i = 0; i < 8; i++) { ss += sm[0][i][c]; ss2 += sm[1][i][c]; }
    part[((size_t)t * BNP + p) * 64 + c] = ss;
    part[((size_t)t * BNP + p) * 64 + 32 + c] = ss2;
  }
}

// ---------------- K3b: finalize BN scale/shift table (T, 2, 32) --------------
__global__ void k_bn2(
    const float* __restrict__ part, const float* __restrict__ gamma,
    const float* __restrict__ beta, float* __restrict__ sctab)
{
  int t = blockIdx.x, c = threadIdx.x;   // 32 threads
  float ss = 0.f, ss2 = 0.f;
#pragma unroll
  for (int p = 0; p < BNP; p++) {
    ss  += part[((size_t)t * BNP + p) * 64 + c];
    ss2 += part[((size_t)t * BNP + p) * 64 + 32 + c];
  }
  float mu = ss * (1.f / BNR);
  float var = ss2 * (1.f / BNR) - mu * mu;
  float rstd = rsqrtf(var + 1e-5f);
  float sc = gamma[c] * rstd;
  sctab[t * 64 + c] = sc;
  sctab[t * 64 + 32 + c] = beta[c] - mu * sc;
}

// ------------- K4: fused BN-apply + 2x GAT per graph → gat_ws (T,B*N,H) ------
__global__ __launch_bounds__(256) void k_gat(
    const float* __restrict__ r, const float* __restrict__ sctab,
    const float* __restrict__ w1, const float* __restrict__ a1, const float* __restrict__ bg1,
    const float* __restrict__ w2, const float* __restrict__ a2, const float* __restrict__ bg2,
    float* __restrict__ gat_ws)
{
  int g = blockIdx.x;          // b*T + t
  int b = g >> 7, t = g & 127;
  int tid = threadIdx.x;
  __shared__ float X[N][H];
  __shared__ float Hm[N][H + 1];   // padded: row-reads conflict-free
  __shared__ float Wl[H * H];
  __shared__ float ssrc[N], sdst[N];
  __shared__ float alph[M][12];
  for (int i = tid; i < N * H; i += 256) {
    int cc = i & 31;
    ((float*)X)[i] = r[(size_t)g * N * H + i] * sctab[t * 64 + cc] + sctab[t * 64 + 32 + cc];
  }
  const float* Ws[2] = {w1, w2};
  const float* As[2] = {a1, a2};
  const float* Bs[2] = {bg1, bg2};
  int oc = tid & 31, n0 = tid >> 5;
  for (int layer = 0; layer < 2; layer++) {
    const float* av = As[layer];
    const float* bias = Bs[layer];
    for (int i = tid; i < H * H; i += 256) Wl[i] = Ws[layer][i];
    __syncthreads();
    // h = X @ W  (48x32 @ 32x32)
#pragma unroll
    for (int rep = 0; rep < 6; rep++) {
      int n = n0 + rep * 8;
      float acc = 0.f;
#pragma unroll
      for (int kk = 0; kk < H; kk++) acc += X[n][kk] * Wl[kk * H + oc];
      Hm[n][oc] = acc;
    }
    __syncthreads();
    if (tid < N) {
      float as = 0.f, ad = 0.f;
#pragma unroll
      for (int kk = 0; kk < H; kk++) {
        float x = Hm[tid][kk];
        as += x * av[kk]; ad += x * av[H + kk];
      }
      ssrc[tid] = as; sdst[tid] = ad;
    }
    __syncthreads();
    if (tid < M) {   // softmax over each root's 12 incoming edges
      float ev[12];
      float sd = sdst[tid * KR + KR - 1];
#pragma unroll
      for (int kp = 0; kp < KLEAF; kp++) ev[kp] = ssrc[tid * KR + kp] + sd;
#pragma unroll
      for (int j = 0; j < 7; j++) {
        int mm = j < tid ? j : j + 1;
        ev[KLEAF + j] = ssrc[mm * KR + KR - 1] + sd;
      }
      float mx = -1e30f;
#pragma unroll
      for (int i = 0; i < 12; i++) {
        float e = ev[i]; e = e > 0.f ? e : 0.2f * e;
        ev[i] = e; mx = fmaxf(mx, e);
      }
      float s = 0.f;
#pragma unroll
      for (int i = 0; i < 12; i++) { float e = __expf(ev[i] - mx); ev[i] = e; s += e; }
      float inv = frcp(s);
#pragma unroll
      for (int i = 0; i < 12; i++) alph[tid][i] = ev[i] * inv;
    }
    __syncthreads();
    float hv[6];
#pragma unroll
    for (int rep = 0; rep < 6; rep++) {
      int n = n0 + rep * 8;
      int m2 = n / KR;
      float acc;
      if (n % KR == KR - 1) {      // root: attention-weighted sum of 12 srcs
        acc = 0.f;
#pragma unroll
        for (int kp = 0; kp < KLEAF; kp++) acc += alph[m2][kp] * Hm[m2 * KR + kp][oc];
#pragma unroll
        for (int j = 0; j < 7; j++) {
          int mm = j < m2 ? j : j + 1;
          acc += alph[m2][KLEAF + j] * Hm[mm * KR + KR - 1][oc];
        }
      } else {                      // leaf: single incoming edge, alpha == 1
        acc = Hm[m2 * KR + KR - 1][oc];
      }
      acc += bias[oc];
      hv[rep] = acc > 0.f ? acc : __expf(acc) - 1.f;   // elu
    }
    __syncthreads();
#pragma unroll
    for (int rep = 0; rep < 6; rep++) X[n0 + rep * 8][oc] = hv[rep];
    __syncthreads();
  }
  for (int i = tid; i < N * H; i += 256)
    gat_ws[((size_t)t * BNR + (size_t)b * N) * H + i] = ((float*)X)[i];
}

extern "C" void kernel_launch(void* const* d_in, const int* in_sizes, int n_in,
                              void* d_out, int out_size, void* d_ws, size_t ws_size,
                              hipStream_t stream)
{
  const float* feat     = (const float*)d_in[0];
  const float* phi_w1   = (const float*)d_in[1];
  const float* phi_b1   = (const float*)d_in[2];
  const float* phi_w2   = (const float*)d_in[3];
  const float* phi_b2   = (const float*)d_in[4];
  const float* spa_wih  = (const float*)d_in[5];
  const float* spa_whh  = (const float*)d_in[6];
  const float* spa_bih  = (const float*)d_in[7];
  const float* spa_bhh  = (const float*)d_in[8];
  const float* bn_gamma = (const float*)d_in[9];
  const float* bn_beta  = (const float*)d_in[10];
  const float* gat1_w   = (const float*)d_in[11];
  const float* gat1_a   = (const float*)d_in[12];
  const float* gat1_b   = (const float*)d_in[13];
  const float* gat2_w   = (const float*)d_in[14];
  const float* gat2_a   = (const float*)d_in[15];
  const float* gat2_b   = (const float*)d_in[16];
  const float* temp_wih = (const float*)d_in[17];
  const float* temp_whh = (const float*)d_in[18];
  const float* temp_bih = (const float*)d_in[19];
  const float* temp_bhh = (const float*)d_in[20];
  float* out = (float*)d_out;

  float* v_ws   = (float*)d_ws;                     // T*BNR*E   = 6.29M floats
  float* gat_ws = v_ws   + (size_t)T * BNR * E;     // T*BNR*H   = 12.58M floats
  float* bnpart = gat_ws + (size_t)T * BNR * H;     // T*BNP*64  = 131072 floats
  float* sctab  = bnpart + (size_t)T * BNP * 64;    // T*64      = 8192 floats

  k_phi <<<(B * T * N + 255) / 256, 256, 0, stream>>>(feat, phi_w1, phi_b1, phi_w2, phi_b2, v_ws);
  k_lstm<16, 0><<<BNR / 2, 256, 0, stream>>>(v_ws, spa_wih, spa_whh, spa_bih, spa_bhh, out);
  k_bn1 <<<dim3(T, BNP), 256, 0, stream>>>(out, bnpart);
  k_bn2 <<<T, 32, 0, stream>>>(bnpart, bn_gamma, bn_beta, sctab);
  k_gat <<<NG, 256, 0, stream>>>(out, sctab, gat1_w, gat1_a, gat1_b, gat2_w, gat2_a, gat2_b, gat_ws);
  k_lstm<32, 1><<<BNR / 2, 256, 0, stream>>>(gat_ws, temp_wih, temp_whh, temp_bih, temp_bhh, out);
}